// Round 3
// baseline (209.266 us; speedup 1.0000x reference)
//
#include <hip/hip_runtime.h>
#include <math.h>

// MultiHeadsGATLayer — algebraic reduction + single-pass coalesced output.
//   s_src[h][n] = x[n] . (W_heads[h] @ a_src[h]),  s_dst likewise
//   atts[h,e] = lrelu(s_src[h][e0] + s_dst[h][e1]); mt = sum_h atts*lin_w + lin_b
//   output = colwise sparse softmax; non-edge cells exp(-1e9-max) == 0 in f32.
// Pipeline: col-CSR -> per-column softmax (compact results) -> row-CSR re-sort
//   -> per-row LDS compose + coalesced float4 stream (output written ONCE).

#define ALPHA 0.2f
constexpr int S = 128;
constexpr int O = 64;
constexpr int H = 4;
constexpr int CAP = 1024;     // max edges per column handled in LDS (avg ~32)
constexpr int MAXN = 8192;    // LDS row buffer size

// --- fold W_heads @ a_heads halves into two 128-vectors per head ---
__global__ void k_wvec(const float* __restrict__ W, const float* __restrict__ a,
                       float* __restrict__ w_src, float* __restrict__ w_dst) {
    int t = blockIdx.x * blockDim.x + threadIdx.x;
    if (t >= H * S) return;
    int h = t / S, s = t % S;
    const float* Wr = W + ((size_t)h * S + s) * O;
    const float* asrc = a + h * 2 * O;
    const float* adst = asrc + O;
    float acc0 = 0.f, acc1 = 0.f;
    for (int o = 0; o < O; ++o) {
        float w = Wr[o];
        acc0 += w * asrc[o];
        acc1 += w * adst[o];
    }
    w_src[h * S + s] = acc0;
    w_dst[h * S + s] = acc1;
}

// --- per-node scalar scores ---
__global__ void k_scores(const float* __restrict__ x, const float* __restrict__ w_src,
                         const float* __restrict__ w_dst, float* __restrict__ s_src,
                         float* __restrict__ s_dst, int N) {
    __shared__ float ws[H * S], wd[H * S];
    for (int i = threadIdx.x; i < H * S; i += blockDim.x) {
        ws[i] = w_src[i];
        wd[i] = w_dst[i];
    }
    __syncthreads();
    int n = blockIdx.x * blockDim.x + threadIdx.x;
    if (n >= N) return;
    const float4* xr = (const float4*)(x + (size_t)n * S);
    float accs[H] = {0, 0, 0, 0}, accd[H] = {0, 0, 0, 0};
    for (int i = 0; i < S / 4; ++i) {
        float4 v = xr[i];
        for (int h = 0; h < H; ++h) {
            const float* wsr = ws + h * S + i * 4;
            const float* wdr = wd + h * S + i * 4;
            accs[h] += v.x * wsr[0] + v.y * wsr[1] + v.z * wsr[2] + v.w * wsr[3];
            accd[h] += v.x * wdr[0] + v.y * wdr[1] + v.z * wdr[2] + v.w * wdr[3];
        }
    }
    for (int h = 0; h < H; ++h) {
        s_src[(size_t)h * N + n] = accs[h];
        s_dst[(size_t)h * N + n] = accd[h];
    }
}

// --- histogram of edges per destination column ---
__global__ void k_hist(const int* __restrict__ edges, int* __restrict__ col_count, int N, int E) {
    int e = blockIdx.x * blockDim.x + threadIdx.x;
    if (e >= E) return;
    int c = edges[(size_t)E + e];
    if ((unsigned)c < (unsigned)N) atomicAdd(&col_count[c], 1);
}

// --- exclusive scan (single block, 256 threads) — used for both col and row CSR ---
__global__ void k_scan(const int* __restrict__ cnt, int* __restrict__ start, int N) {
    __shared__ int part[256];
    int t = threadIdx.x;
    int chunk = (N + 255) / 256;
    int base = t * chunk;
    int s = 0;
    for (int i = 0; i < chunk; ++i)
        if (base + i < N) s += cnt[base + i];
    part[t] = s;
    __syncthreads();
    for (int off = 1; off < 256; off <<= 1) {
        int v = (t >= off) ? part[t - off] : 0;
        __syncthreads();
        part[t] += v;
        __syncthreads();
    }
    int excl = (t == 0) ? 0 : part[t - 1];
    for (int i = 0; i < chunk && base + i < N; ++i) {
        start[base + i] = excl;
        excl += cnt[base + i];
    }
    if (t == 255) start[N] = excl;
}

// --- per-edge logit + head combine, scatter into column-sorted CSR ---
__global__ void k_scatter(const int* __restrict__ edges, const float* __restrict__ values,
                          const float* __restrict__ s_src, const float* __restrict__ s_dst,
                          const float* __restrict__ lin_w, const float* __restrict__ lin_b,
                          const int* __restrict__ col_start, int* __restrict__ col_cursor,
                          int* __restrict__ row_sorted, int* __restrict__ col_sorted,
                          float* __restrict__ val_sorted, float* __restrict__ aval_sorted,
                          int N, int E) {
    int e = blockIdx.x * blockDim.x + threadIdx.x;
    if (e >= E) return;
    int r = edges[e];
    int c = edges[(size_t)E + e];
    if ((unsigned)r >= (unsigned)N || (unsigned)c >= (unsigned)N) return;
    float mt = lin_b[0];
#pragma unroll
    for (int h = 0; h < H; ++h) {
        float att = s_src[(size_t)h * N + r] + s_dst[(size_t)h * N + c];
        att = att >= 0.f ? att : ALPHA * att;
        mt += att * lin_w[h];
    }
    float nv = values[e] * mt;
    int pos = col_start[c] + atomicAdd(&col_cursor[c], 1);
    row_sorted[pos] = r;
    col_sorted[pos] = c;
    val_sorted[pos] = nv;
    aval_sorted[pos] = values[e];
}

// --- per-column sparse softmax; emit compact results + row histogram ---
// rowkeep[k] = row for the "first" entry of each distinct (row,col); -1 for dups.
// res[k] = softmax value for first entries.
__global__ void k_softmax_compact(const int* __restrict__ col_start, const int* __restrict__ row_sorted,
                                  const float* __restrict__ val_sorted, const float* __restrict__ aval_sorted,
                                  int* __restrict__ rowkeep, float* __restrict__ res,
                                  int* __restrict__ row_count, int N) {
    int j = blockIdx.x;
    int beg = col_start[j], end = col_start[j + 1];
    int m = end - beg;
    int lane = threadIdx.x;
    if (m == 0) return;  // empty column handled by row-writer via empty list

    __shared__ int rws[CAP];
    __shared__ float vls[CAP], avl[CAP], vcb[CAP];

    if (m <= CAP) {
        for (int k = lane; k < m; k += 64) {
            rws[k] = row_sorted[beg + k];
            vls[k] = val_sorted[beg + k];
            avl[k] = aval_sorted[beg + k];
        }
        __syncthreads();
        float lmax = -INFINITY;
        for (int k = lane; k < m; k += 64) {
            int rk = rws[k];
            bool first = true;
            for (int l = 0; l < k; ++l)
                if (rws[l] == rk) { first = false; break; }
            float v = -INFINITY;
            if (first) {
                float dsum = 0.f, asum = 0.f;
                for (int l = 0; l < m; ++l)
                    if (rws[l] == rk) { dsum += vls[l]; asum += avl[l]; }
                float mask = (asum == 1.0f) ? 0.0f : asum;
                v = dsum + mask;
                lmax = fmaxf(lmax, v);
            }
            vcb[k] = v;
        }
#pragma unroll
        for (int off = 32; off; off >>= 1) lmax = fmaxf(lmax, __shfl_xor(lmax, off));
        __syncthreads();
        float lsum = 0.f;
        for (int k = lane; k < m; k += 64) {
            float v = vcb[k];
            if (v != -INFINITY) lsum += expf(v - lmax);
        }
#pragma unroll
        for (int off = 32; off; off >>= 1) lsum += __shfl_xor(lsum, off);
        float inv = 1.0f / lsum;
        for (int k = lane; k < m; k += 64) {
            float v = vcb[k];
            if (v != -INFINITY) {
                res[beg + k] = expf(v - lmax) * inv;
                rowkeep[beg + k] = rws[k];
                atomicAdd(&row_count[rws[k]], 1);
            } else {
                rowkeep[beg + k] = -1;
            }
        }
    } else {
        // generic global-memory path (m > CAP; not expected with avg degree ~32)
        float lmax = -INFINITY;
        for (int k = lane; k < m; k += 64) {
            int rk = row_sorted[beg + k];
            bool first = true;
            for (int l = 0; l < k; ++l)
                if (row_sorted[beg + l] == rk) { first = false; break; }
            if (first) {
                float dsum = 0.f, asum = 0.f;
                for (int l = 0; l < m; ++l)
                    if (row_sorted[beg + l] == rk) { dsum += val_sorted[beg + l]; asum += aval_sorted[beg + l]; }
                float mask = (asum == 1.0f) ? 0.0f : asum;
                lmax = fmaxf(lmax, dsum + mask);
            }
        }
#pragma unroll
        for (int off = 32; off; off >>= 1) lmax = fmaxf(lmax, __shfl_xor(lmax, off));
        float lsum = 0.f;
        for (int k = lane; k < m; k += 64) {
            int rk = row_sorted[beg + k];
            bool first = true;
            for (int l = 0; l < k; ++l)
                if (row_sorted[beg + l] == rk) { first = false; break; }
            if (first) {
                float dsum = 0.f, asum = 0.f;
                for (int l = 0; l < m; ++l)
                    if (row_sorted[beg + l] == rk) { dsum += val_sorted[beg + l]; asum += aval_sorted[beg + l]; }
                float mask = (asum == 1.0f) ? 0.0f : asum;
                lsum += expf(dsum + mask - lmax);
            }
        }
#pragma unroll
        for (int off = 32; off; off >>= 1) lsum += __shfl_xor(lsum, off);
        float inv = 1.0f / lsum;
        for (int k = lane; k < m; k += 64) {
            int rk = row_sorted[beg + k];
            bool first = true;
            for (int l = 0; l < k; ++l)
                if (row_sorted[beg + l] == rk) { first = false; break; }
            if (first) {
                float dsum = 0.f, asum = 0.f;
                for (int l = 0; l < m; ++l)
                    if (row_sorted[beg + l] == rk) { dsum += val_sorted[beg + l]; asum += aval_sorted[beg + l]; }
                float mask = (asum == 1.0f) ? 0.0f : asum;
                res[beg + k] = expf(dsum + mask - lmax) * inv;
                rowkeep[beg + k] = rk;
                atomicAdd(&row_count[rk], 1);
            } else {
                rowkeep[beg + k] = -1;
            }
        }
    }
}

// --- re-sort kept results by row ---
__global__ void k_scatter_row(const int* __restrict__ rowkeep, const int* __restrict__ col_sorted,
                              const float* __restrict__ res, const int* __restrict__ row_start,
                              int* __restrict__ row_cursor, int* __restrict__ col_r,
                              float* __restrict__ val_r, int E) {
    int k = blockIdx.x * blockDim.x + threadIdx.x;
    if (k >= E) return;
    int r = rowkeep[k];
    if (r < 0) return;
    int pos = row_start[r] + atomicAdd(&row_cursor[r], 1);
    col_r[pos] = col_sorted[k];
    val_r[pos] = res[k];
}

// --- list of empty columns (uniform 1/N softmax) ---
__global__ void k_emptycols(const int* __restrict__ col_start, int* __restrict__ empty_list,
                            int* __restrict__ empty_cnt, int N) {
    int j = blockIdx.x * blockDim.x + threadIdx.x;
    if (j >= N) return;
    if (col_start[j + 1] == col_start[j]) {
        int p = atomicAdd(empty_cnt, 1);
        empty_list[p] = j;
    }
}

// --- per-row compose in LDS + coalesced float4 stream (output written once) ---
__global__ void __launch_bounds__(256) k_rowwrite(const int* __restrict__ row_start,
                                                  const int* __restrict__ col_r,
                                                  const float* __restrict__ val_r,
                                                  const int* __restrict__ empty_list,
                                                  const int* __restrict__ empty_cnt,
                                                  float* __restrict__ out, int N) {
    __shared__ float lrow[MAXN];
    int i = blockIdx.x;
    int t = threadIdx.x;
    float4* l4 = (float4*)lrow;
    int n4 = N / 4;
    for (int k = t; k < n4; k += 256) l4[k] = make_float4(0.f, 0.f, 0.f, 0.f);
    __syncthreads();
    int beg = row_start[i], end = row_start[i + 1];
    for (int k = beg + t; k < end; k += 256) lrow[col_r[k]] = val_r[k];
    int ec = empty_cnt[0];
    if (ec > 0) {
        float v = 1.0f / (float)N;
        for (int k = t; k < ec; k += 256) lrow[empty_list[k]] = v;
    }
    __syncthreads();
    float4* o4 = (float4*)(out + (size_t)i * N);
    for (int k = t; k < n4; k += 256) o4[k] = l4[k];
}

extern "C" void kernel_launch(void* const* d_in, const int* in_sizes, int n_in,
                              void* d_out, int out_size, void* d_ws, size_t ws_size,
                              hipStream_t stream) {
    const float* x = (const float*)d_in[0];
    const int* edges = (const int*)d_in[1];      // harness: integer inputs are int32
    const float* values = (const float*)d_in[2];
    const float* W = (const float*)d_in[3];
    const float* a = (const float*)d_in[4];
    const float* lin_w = (const float*)d_in[5];
    const float* lin_b = (const float*)d_in[6];
    float* out = (float*)d_out;

    const int N = in_sizes[0] / S;   // 8192
    const int E = in_sizes[2];       // 262144

    // workspace layout (256B-aligned slabs)
    char* wsb = (char*)d_ws;
    size_t off = 0;
    auto alloc = [&](size_t bytes) -> void* {
        void* p = wsb + off;
        off += (bytes + 255) & ~(size_t)255;
        return p;
    };
    float* w_src = (float*)alloc((size_t)H * S * 4);
    float* w_dst = (float*)alloc((size_t)H * S * 4);
    float* s_src = (float*)alloc((size_t)H * N * 4);
    float* s_dst = (float*)alloc((size_t)H * N * 4);
    int* col_count = (int*)alloc((size_t)N * 4);
    int* col_start = (int*)alloc((size_t)(N + 1) * 4);
    int* col_cursor = (int*)alloc((size_t)N * 4);
    int* row_count = (int*)alloc((size_t)N * 4);
    int* row_start = (int*)alloc((size_t)(N + 1) * 4);
    int* row_cursor = (int*)alloc((size_t)N * 4);
    int* row_sorted = (int*)alloc((size_t)E * 4);
    int* col_sorted = (int*)alloc((size_t)E * 4);
    float* val_sorted = (float*)alloc((size_t)E * 4);
    float* aval_sorted = (float*)alloc((size_t)E * 4);
    int* rowkeep = (int*)alloc((size_t)E * 4);
    float* res = (float*)alloc((size_t)E * 4);
    int* col_r = (int*)alloc((size_t)E * 4);
    float* val_r = (float*)alloc((size_t)E * 4);
    int* empty_list = (int*)alloc((size_t)N * 4);
    int* empty_cnt = (int*)alloc(256);

    hipMemsetAsync(col_count, 0, (size_t)N * sizeof(int), stream);
    hipMemsetAsync(col_cursor, 0, (size_t)N * sizeof(int), stream);
    hipMemsetAsync(row_count, 0, (size_t)N * sizeof(int), stream);
    hipMemsetAsync(row_cursor, 0, (size_t)N * sizeof(int), stream);
    hipMemsetAsync(rowkeep, 0xFF, (size_t)E * sizeof(int), stream);
    hipMemsetAsync(empty_cnt, 0, sizeof(int), stream);

    k_wvec<<<(H * S + 255) / 256, 256, 0, stream>>>(W, a, w_src, w_dst);
    k_scores<<<(N + 255) / 256, 256, 0, stream>>>(x, w_src, w_dst, s_src, s_dst, N);
    k_hist<<<(E + 255) / 256, 256, 0, stream>>>(edges, col_count, N, E);
    k_scan<<<1, 256, 0, stream>>>(col_count, col_start, N);
    k_scatter<<<(E + 255) / 256, 256, 0, stream>>>(edges, values, s_src, s_dst, lin_w, lin_b,
                                                   col_start, col_cursor, row_sorted, col_sorted,
                                                   val_sorted, aval_sorted, N, E);
    k_softmax_compact<<<N, 64, 0, stream>>>(col_start, row_sorted, val_sorted, aval_sorted,
                                            rowkeep, res, row_count, N);
    k_scan<<<1, 256, 0, stream>>>(row_count, row_start, N);
    k_scatter_row<<<(E + 255) / 256, 256, 0, stream>>>(rowkeep, col_sorted, res, row_start,
                                                       row_cursor, col_r, val_r, E);
    k_emptycols<<<(N + 255) / 256, 256, 0, stream>>>(col_start, empty_list, empty_cnt, N);
    k_rowwrite<<<N, 256, 0, stream>>>(row_start, col_r, val_r, empty_list, empty_cnt, out, N);
}